// Round 15
// baseline (157.305 us; speedup 1.0000x reference)
//
#include <hip/hip_runtime.h>
#include <hip/hip_bf16.h>
#include <hip/hip_fp16.h>
#include <math.h>

#define N_NODES 8192
#define KNN 32

typedef unsigned short ushort_t;
typedef ushort_t ushort8 __attribute__((ext_vector_type(8)));
typedef ushort_t ushort4v __attribute__((ext_vector_type(4)));
typedef short short8v __attribute__((ext_vector_type(8)));
typedef float f32x4 __attribute__((ext_vector_type(4)));

static __device__ __forceinline__ float b2f(ushort_t u) {
    union { float f; unsigned int i; } v; v.i = ((unsigned int)u) << 16; return v.f;
}
static __device__ __forceinline__ ushort_t f2b(float f) {
    __hip_bfloat16 h = __float2bfloat16(f);
    return *(ushort_t*)&h;
}
static __device__ __forceinline__ float h2f(ushort_t u) {
    __half h = *(__half*)&u; return __half2float(h);
}
static __device__ __forceinline__ ushort_t f2h(float f) {
    __half h = __float2half(f); return *(ushort_t*)&h;
}

// ---------------------------------------------------------------------------
// build_weights: pre-transposed bf16 weight tables (one launch).
// ---------------------------------------------------------------------------
#define N_WALLT (1152 * 384)
#define N_WCATT (64 * 128)
#define N_WOUTT (384 * 960)
__global__ void build_weights(
    const float* __restrict__ wq,  const float* __restrict__ bq,
    const float* __restrict__ wkv, const float* __restrict__ bkv,
    const float* __restrict__ wqp, const float* __restrict__ bqp,
    const float* __restrict__ wkvp,const float* __restrict__ bkvp,
    const float* __restrict__ wb,  const float* __restrict__ bb,
    const float* __restrict__ wdz, const float* __restrict__ bdz,
    const float* __restrict__ wout,
    ushort_t* __restrict__ WallT, float* __restrict__ ball,
    ushort_t* __restrict__ WcatT, float* __restrict__ bcat,
    ushort_t* __restrict__ WoutT)
{
    int t = blockIdx.x * 256 + threadIdx.x;
    if (t < N_WALLT) {
        const int p = t / 384, k = t % 384;
        float v;
        if      (p < 192) v = wq  [k * 192 + p];
        else if (p < 576) v = wkv [k * 384 + (p - 192)];
        else if (p < 720) v = wqp [k * 144 + (p - 576)];
        else              v = wkvp[k * 432 + (p - 720)];
        WallT[t] = f2b(v);
    } else if (t < N_WALLT + N_WCATT) {
        const int u = t - N_WALLT;
        const int j = u >> 7, c = u & 127;
        float v = (j < 12) ? wb[c * 12 + j] : (j < 44 ? wdz[c * 32 + (j - 12)] : 0.0f);
        WcatT[u] = f2b(v);
    } else if (t < N_WALLT + N_WCATT + N_WOUTT) {
        const int u = t - N_WALLT - N_WCATT;
        const int p = u / 960, k = u % 960;
        WoutT[u] = f2b(wout[k * 384 + p]);
    } else {
        const int u = t - N_WALLT - N_WCATT - N_WOUTT;
        if (u < 1152) {
            float v;
            if      (u < 192)  v = bq[u];
            else if (u < 576)  v = bkv[u - 192];
            else if (u < 720)  v = bqp[u - 576];
            else               v = bkvp[u - 720];
            ball[u] = v;
        } else if (u < 1152 + 44) {
            const int w = u - 1152;
            bcat[w] = (w < 12) ? bb[w] : bdz[w - 12];
        }
    }
}
#define BW_TOTAL (N_WALLT + N_WCATT + N_WOUTT + 1152 + 44)

// ---------------------------------------------------------------------------
// s-projection GEMM, 128x128 tile, XCD-affine swizzle, SPLIT epilogue:
//   cols   0..191 -> qb  bf16 [n][192]
//   cols 192..575 -> kbt/vbt bf16 [n][192]
//   cols 576..1151-> praw fp16 [n][576]   (NEW: fp16)
// ---------------------------------------------------------------------------
__global__ __launch_bounds__(256) void gemm_sproj(
    const float* __restrict__ A, const ushort_t* __restrict__ WT,
    const float* __restrict__ bias,
    ushort_t* __restrict__ qb, ushort_t* __restrict__ kbt,
    ushort_t* __restrict__ vbt, ushort_t* __restrict__ praw)
{
    __shared__ ushort_t As[128][40];
    __shared__ ushort_t Bs[128][40];

    const int tid  = threadIdx.x;
    const int ncol = 9;
    const int id   = blockIdx.x;
    const int xcd  = id & 7;
    const int qq   = id >> 3;
    const int row0 = ((qq / ncol) * 8 + xcd) * 128;
    const int col0 = (qq % ncol) * 128;
    const int K    = 384;

    const int wave = tid >> 6;
    const int lane = tid & 63;
    const int wm = (wave >> 1) * 64;
    const int wn = (wave & 1) * 64;
    const int m16 = lane & 15;
    const int kof = (lane >> 4) * 8;

    const int a_row = tid >> 1;
    const int a_kq  = (tid & 1) * 16;

    f32x4 acc[4][4];
#pragma unroll
    for (int i = 0; i < 4; ++i)
#pragma unroll
        for (int j = 0; j < 4; ++j) acc[i][j] = (f32x4)0.0f;

    for (int k0 = 0; k0 < K; k0 += 32) {
        {
            const float* ap = A + (size_t)(row0 + a_row) * K + (k0 + a_kq);
            float4 v0 = *(const float4*)(ap);
            float4 v1 = *(const float4*)(ap + 4);
            float4 v2 = *(const float4*)(ap + 8);
            float4 v3 = *(const float4*)(ap + 12);
            ushort8 u0, u1;
            u0[0] = f2b(v0.x); u0[1] = f2b(v0.y); u0[2] = f2b(v0.z); u0[3] = f2b(v0.w);
            u0[4] = f2b(v1.x); u0[5] = f2b(v1.y); u0[6] = f2b(v1.z); u0[7] = f2b(v1.w);
            u1[0] = f2b(v2.x); u1[1] = f2b(v2.y); u1[2] = f2b(v2.z); u1[3] = f2b(v2.w);
            u1[4] = f2b(v3.x); u1[5] = f2b(v3.y); u1[6] = f2b(v3.z); u1[7] = f2b(v3.w);
            *(ushort8*)&As[a_row][a_kq]     = u0;
            *(ushort8*)&As[a_row][a_kq + 8] = u1;
        }
        {
            const ushort_t* wp = WT + (size_t)(col0 + a_row) * K + (k0 + a_kq);
            *(ushort8*)&Bs[a_row][a_kq]     = *(const ushort8*)(wp);
            *(ushort8*)&Bs[a_row][a_kq + 8] = *(const ushort8*)(wp + 8);
        }
        __syncthreads();

        short8v a[4], b[4];
#pragma unroll
        for (int mb = 0; mb < 4; ++mb)
            a[mb] = *(const short8v*)&As[wm + mb * 16 + m16][kof];
#pragma unroll
        for (int nb = 0; nb < 4; ++nb)
            b[nb] = *(const short8v*)&Bs[wn + nb * 16 + m16][kof];
#pragma unroll
        for (int mb = 0; mb < 4; ++mb)
#pragma unroll
            for (int nb = 0; nb < 4; ++nb)
                acc[mb][nb] = __builtin_amdgcn_mfma_f32_16x16x32_bf16(
                    a[mb], b[nb], acc[mb][nb], 0, 0, 0);
        __syncthreads();
    }

    const int r_base = row0 + wm + (lane >> 4) * 4;
#pragma unroll
    for (int nb = 0; nb < 4; ++nb) {
        const int col = col0 + wn + nb * 16 + m16;
        const float bv = bias[col];
#pragma unroll
        for (int mb = 0; mb < 4; ++mb) {
#pragma unroll
            for (int r = 0; r < 4; ++r) {
                const int row = r_base + mb * 16 + r;
                const float v = acc[mb][nb][r] + bv;
                if (col < 192) {
                    qb[(size_t)row * 192 + col] = f2b(v);
                } else if (col < 576) {
                    const int u = col - 192, h = u >> 5, c = u & 31;
                    if (c < 16) kbt[(size_t)row * 192 + h * 16 + c] = f2b(v);
                    else        vbt[(size_t)row * 192 + h * 16 + (c - 16)] = f2b(v);
                } else {
                    praw[(size_t)row * 576 + (col - 576)] = f2h(v);
                }
            }
        }
    }
}

// ---------------------------------------------------------------------------
// z-projection GEMM, single-stage (K=128 staged once, 1 barrier).
// ---------------------------------------------------------------------------
__global__ __launch_bounds__(256) void gemm_zproj(
    const float* __restrict__ Z, const ushort_t* __restrict__ WcT,
    const float* __restrict__ bc, ushort_t* __restrict__ zph)
{
    __shared__ ushort_t zt[64][136];
    __shared__ ushort_t wt[64][136];

    const int tid  = threadIdx.x;
    const int row0 = blockIdx.x * 64;
    const int wave = tid >> 6;
    const int lane = tid & 63;
    const int wm = (wave >> 1) * 32;
    const int wn = (wave & 1) * 32;
    const int m16 = lane & 15;
    const int kof = (lane >> 4) * 8;

    const int r  = tid >> 2;
    const int qt = (tid & 3) * 32;

    {
        const float* ap = Z + (size_t)(row0 + r) * 128 + qt;
#pragma unroll
        for (int i = 0; i < 4; ++i) {
            float4 v0 = *(const float4*)(ap + i * 8);
            float4 v1 = *(const float4*)(ap + i * 8 + 4);
            ushort8 u;
            u[0] = f2b(v0.x); u[1] = f2b(v0.y); u[2] = f2b(v0.z); u[3] = f2b(v0.w);
            u[4] = f2b(v1.x); u[5] = f2b(v1.y); u[6] = f2b(v1.z); u[7] = f2b(v1.w);
            *(ushort8*)&zt[r][qt + i * 8] = u;
        }
    }
    {
        const ushort_t* wp = WcT + (size_t)r * 128 + qt;
        *(ushort8*)&wt[r][qt]      = *(const ushort8*)(wp);
        *(ushort8*)&wt[r][qt + 8]  = *(const ushort8*)(wp + 8);
        *(ushort8*)&wt[r][qt + 16] = *(const ushort8*)(wp + 16);
        *(ushort8*)&wt[r][qt + 24] = *(const ushort8*)(wp + 24);
    }
    __syncthreads();

    f32x4 acc[2][2];
#pragma unroll
    for (int i = 0; i < 2; ++i)
#pragma unroll
        for (int j = 0; j < 2; ++j) acc[i][j] = (f32x4)0.0f;

#pragma unroll
    for (int ks = 0; ks < 4; ++ks) {
        short8v a[2], b[2];
        a[0] = *(const short8v*)&zt[wm + m16][ks * 32 + kof];
        a[1] = *(const short8v*)&zt[wm + 16 + m16][ks * 32 + kof];
        b[0] = *(const short8v*)&wt[wn + m16][ks * 32 + kof];
        b[1] = *(const short8v*)&wt[wn + 16 + m16][ks * 32 + kof];
#pragma unroll
        for (int mb = 0; mb < 2; ++mb)
#pragma unroll
            for (int nb = 0; nb < 2; ++nb)
                acc[mb][nb] = __builtin_amdgcn_mfma_f32_16x16x32_bf16(
                    a[mb], b[nb], acc[mb][nb], 0, 0, 0);
    }

    const int r_base = row0 + wm + (lane >> 4) * 4;
#pragma unroll
    for (int nb = 0; nb < 2; ++nb) {
        const int col = wn + nb * 16 + m16;
        if (col >= 44) continue;
        const float bv = bc[col];
#pragma unroll
        for (int mb = 0; mb < 2; ++mb) {
#pragma unroll
            for (int rr = 0; rr < 4; ++rr) {
                zph[(size_t)(r_base + mb * 16 + rr) * 48 + col] = f2b(acc[mb][nb][rr] + bv);
            }
        }
    }
}

// ---------------------------------------------------------------------------
// out-GEMM: A bf16 (catb), B = WoutT[384][960] bf16, 64x64, XCD swizzle.
// ---------------------------------------------------------------------------
__global__ __launch_bounds__(256) void gemm_out(
    const ushort_t* __restrict__ A, const ushort_t* __restrict__ WT,
    const float* __restrict__ bias, float* __restrict__ C)
{
    __shared__ ushort_t As[64][40];
    __shared__ ushort_t Bs[64][40];

    const int tid  = threadIdx.x;
    const int ncol = 6;
    const int id   = blockIdx.x;
    const int xcd  = id & 7;
    const int qq   = id >> 3;
    const int row0 = ((qq / ncol) * 8 + xcd) * 64;
    const int col0 = (qq % ncol) * 64;
    const int K = 960, P = 384;

    const int wave = tid >> 6;
    const int lane = tid & 63;
    const int wm = (wave >> 1) * 32;
    const int wn = (wave & 1) * 32;
    const int m16 = lane & 15;
    const int kof = (lane >> 4) * 8;

    const int a_row = tid >> 2;
    const int a_kq  = (tid & 3) * 8;

    f32x4 acc[2][2];
#pragma unroll
    for (int i = 0; i < 2; ++i)
#pragma unroll
        for (int j = 0; j < 2; ++j) acc[i][j] = (f32x4)0.0f;

    for (int k0 = 0; k0 < K; k0 += 32) {
        *(ushort8*)&As[a_row][a_kq] =
            *(const ushort8*)(A + (size_t)(row0 + a_row) * K + (k0 + a_kq));
        *(ushort8*)&Bs[a_row][a_kq] =
            *(const ushort8*)(WT + (size_t)(col0 + a_row) * K + (k0 + a_kq));
        __syncthreads();

        short8v a[2], b[2];
#pragma unroll
        for (int mb = 0; mb < 2; ++mb)
            a[mb] = *(const short8v*)&As[wm + mb * 16 + m16][kof];
#pragma unroll
        for (int nb = 0; nb < 2; ++nb)
            b[nb] = *(const short8v*)&Bs[wn + nb * 16 + m16][kof];
#pragma unroll
        for (int mb = 0; mb < 2; ++mb)
#pragma unroll
            for (int nb = 0; nb < 2; ++nb)
                acc[mb][nb] = __builtin_amdgcn_mfma_f32_16x16x32_bf16(
                    a[mb], b[nb], acc[mb][nb], 0, 0, 0);
        __syncthreads();
    }

    const int r_base = row0 + wm + (lane >> 4) * 4;
#pragma unroll
    for (int nb = 0; nb < 2; ++nb) {
        const int col = col0 + wn + nb * 16 + m16;
        const float bv = bias[col];
#pragma unroll
        for (int mb = 0; mb < 2; ++mb) {
#pragma unroll
            for (int r = 0; r < 4; ++r) {
                C[(size_t)(r_base + mb * 16 + r) * P + col] = acc[mb][nb][r] + bv;
            }
        }
    }
}

// ---------------------------------------------------------------------------
// prep_pts: praw fp16 in; q_pts fp32, kpt fp16, vpt bf16 out. 192 tasks/node.
// ---------------------------------------------------------------------------
__global__ void prep_pts(const ushort_t* __restrict__ praw,
                         const float* __restrict__ rot,
                         const float* __restrict__ trans,
                         float* __restrict__ q_pts,
                         ushort_t* __restrict__ kpt,
                         ushort_t* __restrict__ vpt)
{
    int t = blockIdx.x * 256 + threadIdx.x;
    if (t >= N_NODES * 192) return;
    const int n = t / 192;
    const int m = t % 192;
    const ushort_t* row = praw + (size_t)n * 576;
    const float* R  = rot + n * 9;
    const float* tr = trans + n * 3;
    float X, Y, Z;
    if (m < 48) { X = h2f(row[m]);       Y = h2f(row[48 + m]);   Z = h2f(row[96 + m]); }
    else { const int pt = m - 48;
           X = h2f(row[144 + pt]);  Y = h2f(row[288 + pt]); Z = h2f(row[432 + pt]); }
    const float gx = R[0] * X + R[1] * Y + R[2] * Z + tr[0];
    const float gy = R[3] * X + R[4] * Y + R[5] * Z + tr[1];
    const float gz = R[6] * X + R[7] * Y + R[8] * Z + tr[2];
    if (m < 48) {
        const int h = m >> 2, p = m & 3;
        float* dst = q_pts + (size_t)n * 144 + h * 12 + p * 3;
        dst[0] = gx; dst[1] = gy; dst[2] = gz;
    } else {
        const int pt = m - 48, h = pt / 12, p = pt % 12;
        if (p < 4) {
            ushort_t* dst = kpt + (size_t)n * 144 + h * 12 + p * 3;
            dst[0] = f2h(gx); dst[1] = f2h(gy); dst[2] = f2h(gz);
        } else {
            ushort_t* dst = vpt + (size_t)n * 288 + h * 24 + (p - 4) * 3;
            dst[0] = f2b(gx); dst[1] = f2b(gy); dst[2] = f2b(gz);
        }
    }
}

// ---------------------------------------------------------------------------
// attention: TWO nodes per block (grid N/2). Same per-task math as round 13;
// phases interleave both nodes' tasks for higher lane utilization / MLP.
// ---------------------------------------------------------------------------
__global__ __launch_bounds__(256, 8) void attn_kernel(
    const ushort_t* __restrict__ qb,       // N x 192 bf16
    const ushort_t* __restrict__ kbt,      // N x 192 bf16
    const ushort_t* __restrict__ vbt,      // N x 192 bf16
    const float* __restrict__ q_pts,       // N x 144 f32
    const ushort_t* __restrict__ kpt,      // N x 144 fp16
    const ushort_t* __restrict__ vpt,      // N x 288 bf16
    const ushort_t* __restrict__ zph,      // (N*K) x 48 bf16 (44 valid)
    const int*   __restrict__ eidx,
    const float* __restrict__ mask,
    const float* __restrict__ rot,
    const float* __restrict__ trans,
    const float* __restrict__ head_weights,
    ushort_t* __restrict__ catb)           // N x 960 bf16
{
    const int n0  = blockIdx.x * 2;
    const int tid = threadIdx.x;

    __shared__ ushort_t zp[2][32][48];
    __shared__ float q_s[2][192];
    __shared__ float qp_s[2][144];
    __shared__ float a_s[2][12][33];
    __shared__ float opt[2][288];
    __shared__ int   idx_s[2][32];
    __shared__ float madd_s[2][32];
    __shared__ float R_s[2][9];
    __shared__ float t_s[2][3];
    __shared__ float hw_s[12];

    // ---- phase 0: stage both nodes' reused data ----
    for (int i = tid; i < 384; i += 256) {
        const int nl = i / 192, c = i % 192;
        q_s[nl][c] = b2f(qb[(size_t)(n0 + nl) * 192 + c]);
    }
    for (int i = tid; i < 288; i += 256) {
        const int nl = i / 144, c = i % 144;
        qp_s[nl][c] = q_pts[(size_t)(n0 + nl) * 144 + c];
    }
    if (tid < 64) {
        const int nl = tid >> 5, jj = tid & 31;
        const int ix = eidx[(n0 + nl) * 32 + jj];
        idx_s[nl][jj]  = ix;
        madd_s[nl][jj] = 100000.0f * (mask[ix] - 1.0f);
    }
    if (tid >= 64 && tid < 82) {
        const int nl = (tid - 64) / 9, e = (tid - 64) % 9;
        R_s[nl][e] = rot[(n0 + nl) * 9 + e];
    }
    if (tid >= 82 && tid < 88) {
        const int nl = (tid - 82) / 3, e = (tid - 82) % 3;
        t_s[nl][e] = trans[(n0 + nl) * 3 + e];
    }
    if (tid >= 88 && tid < 100) {
        float x = head_weights[tid - 88];
        hw_s[tid - 88] = log1pf(__expf(x)) * 0.13608276348795434f; // softplus*sqrt(1/54)
    }
    for (int c = tid; c < 384; c += 256) {
        const int nl = c / 192, cc = c % 192;
        const int r = cc / 6, sg = cc % 6;
        *(ushort8*)&zp[nl][r][sg * 8] =
            *(const ushort8*)(zph + ((size_t)(n0 + nl) * 32 + r) * 48 + sg * 8);
    }
    __syncthreads();

    // ---- phase 1: logits, 768 tasks (2 nodes x 12h x 32j) ----
    for (int t = tid; t < 768; t += 256) {
        const int nl = t / 384, tt = t % 384;
        const int h = tt >> 5, j = tt & 31;
        const int ix = idx_s[nl][j];
        const ushort_t* kr = kbt + (size_t)ix * 192 + h * 16;
        ushort8 k0 = *(const ushort8*)(kr);
        ushort8 k1 = *(const ushort8*)(kr + 8);
        const ushort_t* kpr = kpt + (size_t)ix * 144 + h * 12;
        ushort4v p0 = *(const ushort4v*)(kpr);
        ushort4v p1 = *(const ushort4v*)(kpr + 4);
        ushort4v p2 = *(const ushort4v*)(kpr + 8);

        const float* qh = q_s[nl] + h * 16;
        float dot = 0.0f;
#pragma unroll
        for (int c = 0; c < 8; ++c) dot += qh[c] * b2f(k0[c]);
#pragma unroll
        for (int c = 0; c < 8; ++c) dot += qh[8 + c] * b2f(k1[c]);

        const float* qp = qp_s[nl] + h * 12;
        float d, pt = 0.0f;
        d = qp[0]  - h2f(p0[0]); pt += d * d;  d = qp[1]  - h2f(p0[1]); pt += d * d;
        d = qp[2]  - h2f(p0[2]); pt += d * d;  d = qp[3]  - h2f(p0[3]); pt += d * d;
        d = qp[4]  - h2f(p1[0]); pt += d * d;  d = qp[5]  - h2f(p1[1]); pt += d * d;
        d = qp[6]  - h2f(p1[2]); pt += d * d;  d = qp[7]  - h2f(p1[3]); pt += d * d;
        d = qp[8]  - h2f(p2[0]); pt += d * d;  d = qp[9]  - h2f(p2[1]); pt += d * d;
        d = qp[10] - h2f(p2[2]); pt += d * d;  d = qp[11] - h2f(p2[3]); pt += d * d;

        a_s[nl][h][j] = 0.14433756729740643f * dot
                      + 0.5773502691896258f * b2f(zp[nl][j][h])
                      - 0.5f * hw_s[h] * pt
                      + madd_s[nl][j];
    }
    __syncthreads();

    // ---- phase 2: parallel softmax (192 threads; 8-lane groups) ----
    if (tid < 192) {
        const int nl = tid / 96, u = tid % 96;
        const int h = u >> 3, g = u & 7;
        float a0 = a_s[nl][h][g * 4 + 0], a1 = a_s[nl][h][g * 4 + 1];
        float a2 = a_s[nl][h][g * 4 + 2], a3 = a_s[nl][h][g * 4 + 3];
        float m = fmaxf(fmaxf(a0, a1), fmaxf(a2, a3));
        m = fmaxf(m, __shfl_xor(m, 1)); m = fmaxf(m, __shfl_xor(m, 2));
        m = fmaxf(m, __shfl_xor(m, 4));
        float e0 = __expf(a0 - m), e1 = __expf(a1 - m);
        float e2 = __expf(a2 - m), e3 = __expf(a3 - m);
        float s = e0 + e1 + e2 + e3;
        s += __shfl_xor(s, 1); s += __shfl_xor(s, 2); s += __shfl_xor(s, 4);
        const float inv = 1.0f / s;
        a_s[nl][h][g * 4 + 0] = e0 * inv; a_s[nl][h][g * 4 + 1] = e1 * inv;
        a_s[nl][h][g * 4 + 2] = e2 * inv; a_s[nl][h][g * 4 + 3] = e3 * inv;
    }
    __syncthreads();

    // ---- phase 3: weighted sums, 432 tasks (2 nodes x 216) ----
    for (int t = tid; t < 432; t += 256) {
        const int nl = t / 216, k = t % 216;
        ushort_t* catn = catb + (size_t)(n0 + nl) * 960;
        if (k < 48) {                        // o: (h, c-quad)
            const int h = k >> 2, cq = k & 3;
            const ushort_t* base = vbt + h * 16 + cq * 4;
            float s0 = 0, s1 = 0, s2 = 0, s3 = 0;
#pragma unroll 8
            for (int j = 0; j < 32; ++j) {
                const int ix = idx_s[nl][j];
                const float aj = a_s[nl][h][j];
                ushort4v v = *(const ushort4v*)(base + (size_t)ix * 192);
                s0 += aj * b2f(v[0]); s1 += aj * b2f(v[1]);
                s2 += aj * b2f(v[2]); s3 += aj * b2f(v[3]);
            }
            ushort4v o = { f2b(s0), f2b(s1), f2b(s2), f2b(s3) };
            *(ushort4v*)&catn[h * 16 + cq * 4] = o;
        } else if (k < 120) {                // o_pt: (h, quad of 24)
            const int u = k - 48;
            const int h = u / 6, rq = u % 6;
            const ushort_t* base = vpt + h * 24 + rq * 4;
            float s0 = 0, s1 = 0, s2 = 0, s3 = 0;
#pragma unroll 8
            for (int j = 0; j < 32; ++j) {
                const int ix = idx_s[nl][j];
                const float aj = a_s[nl][h][j];
                ushort4v v = *(const ushort4v*)(base + (size_t)ix * 288);
                s0 += aj * b2f(v[0]); s1 += aj * b2f(v[1]);
                s2 += aj * b2f(v[2]); s3 += aj * b2f(v[3]);
            }
            float* od = opt[nl] + h * 24 + rq * 4;
            od[0] = s0; od[1] = s1; od[2] = s2; od[3] = s3;
        } else {                             // o_pair: (h, c-quad of 32)
            const int u = k - 120;
            const int h = u >> 3, cq = u & 7;
            float s0 = 0, s1 = 0, s2 = 0, s3 = 0;
#pragma unroll 8
            for (int j = 0; j < 32; ++j) {
                const float aj = a_s[nl][h][j];
                ushort4v zv = *(const ushort4v*)&zp[nl][j][12 + cq * 4];
                s0 += aj * b2f(zv[0]); s1 += aj * b2f(zv[1]);
                s2 += aj * b2f(zv[2]); s3 += aj * b2f(zv[3]);
            }
            ushort4v o = { f2b(s0), f2b(s1), f2b(s2), f2b(s3) };
            *(ushort4v*)&catn[576 + h * 32 + cq * 4] = o;
        }
    }
    __syncthreads();

    // ---- phase 4: rotate back + norms (192 threads) ----
    if (tid < 192) {
        const int nl = tid / 96, u = tid % 96;
        const int h = u >> 3, p = u & 7;
        ushort_t* catn = catb + (size_t)(n0 + nl) * 960;
        const float* ob = opt[nl] + h * 24 + p * 3;
        float gx = ob[0] - t_s[nl][0];
        float gy = ob[1] - t_s[nl][1];
        float gz = ob[2] - t_s[nl][2];
        float lx = R_s[nl][0] * gx + R_s[nl][3] * gy + R_s[nl][6] * gz;
        float ly = R_s[nl][1] * gx + R_s[nl][4] * gy + R_s[nl][7] * gz;
        float lz = R_s[nl][2] * gx + R_s[nl][5] * gy + R_s[nl][8] * gz;
        const int hp = h * 8 + p;
        catn[192 + hp] = f2b(lx);
        catn[288 + hp] = f2b(ly);
        catn[384 + hp] = f2b(lz);
        catn[480 + hp] = f2b(sqrtf(lx * lx + ly * ly + lz * lz + 1e-8f));
    }
}

// ---------------------------------------------------------------------------
extern "C" void kernel_launch(void* const* d_in, const int* in_sizes, int n_in,
                              void* d_out, int out_size, void* d_ws, size_t ws_size,
                              hipStream_t stream)
{
    const float* s     = (const float*)d_in[0];
    const float* z     = (const float*)d_in[1];
    const int*   eidx  = (const int*)  d_in[2];
    const float* rot   = (const float*)d_in[3];
    const float* trans = (const float*)d_in[4];
    const float* mask  = (const float*)d_in[5];
    const float* w_q   = (const float*)d_in[6];
    const float* b_q   = (const float*)d_in[7];
    const float* w_kv  = (const float*)d_in[8];
    const float* b_kv  = (const float*)d_in[9];
    const float* w_qp  = (const float*)d_in[10];
    const float* b_qp  = (const float*)d_in[11];
    const float* w_kvp = (const float*)d_in[12];
    const float* b_kvp = (const float*)d_in[13];
    const float* w_b   = (const float*)d_in[14];
    const float* b_b   = (const float*)d_in[15];
    const float* w_dz  = (const float*)d_in[16];
    const float* b_dz  = (const float*)d_in[17];
    const float* hw    = (const float*)d_in[18];
    const float* w_out = (const float*)d_in[19];
    const float* b_out = (const float*)d_in[20];
    float* out = (float*)d_out;

    float* ws = (float*)d_ws;
    size_t off = 0;
    ushort_t* qb    = (ushort_t*)(ws + off); off += (size_t)N_NODES * 96;   // 192 bf16
    ushort_t* kbt   = (ushort_t*)(ws + off); off += (size_t)N_NODES * 96;
    ushort_t* vbt   = (ushort_t*)(ws + off); off += (size_t)N_NODES * 96;
    ushort_t* praw  = (ushort_t*)(ws + off); off += (size_t)N_NODES * 288;  // 576 fp16
    float* q_pts    = ws + off;              off += (size_t)N_NODES * 144;
    ushort_t* kpt   = (ushort_t*)(ws + off); off += (size_t)N_NODES * 72;   // 144 fp16
    ushort_t* vpt   = (ushort_t*)(ws + off); off += (size_t)N_NODES * 144;  // 288 bf16
    ushort_t* zph   = (ushort_t*)(ws + off); off += (size_t)N_NODES * KNN * 24; // 48 bf16
    ushort_t* catb  = (ushort_t*)(ws + off); off += (size_t)N_NODES * 480;      // 960 bf16
    ushort_t* WallT = (ushort_t*)(ws + off); off += N_WALLT / 2;
    float* ball     = ws + off;              off += 1152;
    ushort_t* WcatT = (ushort_t*)(ws + off); off += N_WCATT / 2;
    float* bcat     = ws + off;              off += 44;
    ushort_t* WoutT = (ushort_t*)(ws + off); off += N_WOUTT / 2;

    // 1) all weight tables (one launch)
    build_weights<<<(BW_TOTAL + 255) / 256, 256, 0, stream>>>(
        w_q, b_q, w_kv, b_kv, w_qp, b_qp, w_kvp, b_kvp,
        w_b, b_b, w_dz, b_dz, w_out, WallT, ball, WcatT, bcat, WoutT);

    // 2) s-projection with split epilogue (qb | kbt/vbt | praw fp16)
    gemm_sproj<<<(N_NODES / 128) * 9, 256, 0, stream>>>(
        s, WallT, ball, qb, kbt, vbt, praw);

    // 3) z-projection -> bf16 zph (single-stage streaming)
    gemm_zproj<<<(N_NODES * KNN) / 64, 256, 0, stream>>>(z, WcatT, bcat, zph);

    // 4) point transforms
    prep_pts<<<(N_NODES * 192 + 255) / 256, 256, 0, stream>>>(
        praw, rot, trans, q_pts, kpt, vpt);

    // 5) attention (2 nodes per block)
    attn_kernel<<<N_NODES / 2, 256, 0, stream>>>(
        qb, kbt, vbt, q_pts, kpt, vpt, zph, eidx, mask, rot, trans, hw, catb);

    // 6) output projection
    gemm_out<<<(N_NODES / 64) * 6, 256, 0, stream>>>(catb, WoutT, b_out, out);
}

// Round 16
// 150.795 us; speedup vs baseline: 1.0432x; 1.0432x over previous
//
#include <hip/hip_runtime.h>
#include <hip/hip_bf16.h>
#include <hip/hip_fp16.h>
#include <math.h>

#define N_NODES 8192
#define KNN 32

typedef unsigned short ushort_t;
typedef ushort_t ushort8 __attribute__((ext_vector_type(8)));
typedef ushort_t ushort4v __attribute__((ext_vector_type(4)));
typedef short short8v __attribute__((ext_vector_type(8)));
typedef float f32x4 __attribute__((ext_vector_type(4)));

static __device__ __forceinline__ float b2f(ushort_t u) {
    union { float f; unsigned int i; } v; v.i = ((unsigned int)u) << 16; return v.f;
}
static __device__ __forceinline__ ushort_t f2b(float f) {
    __hip_bfloat16 h = __float2bfloat16(f);
    return *(ushort_t*)&h;
}
static __device__ __forceinline__ float h2f(ushort_t u) {
    __half h = *(__half*)&u; return __half2float(h);
}
static __device__ __forceinline__ ushort_t f2h(float f) {
    __half h = __float2half(f); return *(ushort_t*)&h;
}

// ---------------------------------------------------------------------------
// build_weights: pre-transposed bf16 weight tables (one launch).
// ---------------------------------------------------------------------------
#define N_WALLT (1152 * 384)
#define N_WCATT (64 * 128)
#define N_WOUTT (384 * 960)
__global__ void build_weights(
    const float* __restrict__ wq,  const float* __restrict__ bq,
    const float* __restrict__ wkv, const float* __restrict__ bkv,
    const float* __restrict__ wqp, const float* __restrict__ bqp,
    const float* __restrict__ wkvp,const float* __restrict__ bkvp,
    const float* __restrict__ wb,  const float* __restrict__ bb,
    const float* __restrict__ wdz, const float* __restrict__ bdz,
    const float* __restrict__ wout,
    ushort_t* __restrict__ WallT, float* __restrict__ ball,
    ushort_t* __restrict__ WcatT, float* __restrict__ bcat,
    ushort_t* __restrict__ WoutT)
{
    int t = blockIdx.x * 256 + threadIdx.x;
    if (t < N_WALLT) {
        const int p = t / 384, k = t % 384;
        float v;
        if      (p < 192) v = wq  [k * 192 + p];
        else if (p < 576) v = wkv [k * 384 + (p - 192)];
        else if (p < 720) v = wqp [k * 144 + (p - 576)];
        else              v = wkvp[k * 432 + (p - 720)];
        WallT[t] = f2b(v);
    } else if (t < N_WALLT + N_WCATT) {
        const int u = t - N_WALLT;
        const int j = u >> 7, c = u & 127;
        float v = (j < 12) ? wb[c * 12 + j] : (j < 44 ? wdz[c * 32 + (j - 12)] : 0.0f);
        WcatT[u] = f2b(v);
    } else if (t < N_WALLT + N_WCATT + N_WOUTT) {
        const int u = t - N_WALLT - N_WCATT;
        const int p = u / 960, k = u % 960;
        WoutT[u] = f2b(wout[k * 384 + p]);
    } else {
        const int u = t - N_WALLT - N_WCATT - N_WOUTT;
        if (u < 1152) {
            float v;
            if      (u < 192)  v = bq[u];
            else if (u < 576)  v = bkv[u - 192];
            else if (u < 720)  v = bqp[u - 576];
            else               v = bkvp[u - 720];
            ball[u] = v;
        } else if (u < 1152 + 44) {
            const int w = u - 1152;
            bcat[w] = (w < 12) ? bb[w] : bdz[w - 12];
        }
    }
}
#define BW_TOTAL (N_WALLT + N_WCATT + N_WOUTT + 1152 + 44)

// ---------------------------------------------------------------------------
// s-projection GEMM, 128x128 tile, XCD-affine swizzle, SPLIT epilogue:
//   cols   0..191 -> qb  bf16 [n][192]
//   cols 192..575 -> kbt/vbt bf16 [n][192]
//   cols 576..1151-> praw fp16 [n][576]
// ---------------------------------------------------------------------------
__global__ __launch_bounds__(256) void gemm_sproj(
    const float* __restrict__ A, const ushort_t* __restrict__ WT,
    const float* __restrict__ bias,
    ushort_t* __restrict__ qb, ushort_t* __restrict__ kbt,
    ushort_t* __restrict__ vbt, ushort_t* __restrict__ praw)
{
    __shared__ ushort_t As[128][40];
    __shared__ ushort_t Bs[128][40];

    const int tid  = threadIdx.x;
    const int ncol = 9;
    const int id   = blockIdx.x;
    const int xcd  = id & 7;
    const int qq   = id >> 3;
    const int row0 = ((qq / ncol) * 8 + xcd) * 128;
    const int col0 = (qq % ncol) * 128;
    const int K    = 384;

    const int wave = tid >> 6;
    const int lane = tid & 63;
    const int wm = (wave >> 1) * 64;
    const int wn = (wave & 1) * 64;
    const int m16 = lane & 15;
    const int kof = (lane >> 4) * 8;

    const int a_row = tid >> 1;
    const int a_kq  = (tid & 1) * 16;

    f32x4 acc[4][4];
#pragma unroll
    for (int i = 0; i < 4; ++i)
#pragma unroll
        for (int j = 0; j < 4; ++j) acc[i][j] = (f32x4)0.0f;

    for (int k0 = 0; k0 < K; k0 += 32) {
        {
            const float* ap = A + (size_t)(row0 + a_row) * K + (k0 + a_kq);
            float4 v0 = *(const float4*)(ap);
            float4 v1 = *(const float4*)(ap + 4);
            float4 v2 = *(const float4*)(ap + 8);
            float4 v3 = *(const float4*)(ap + 12);
            ushort8 u0, u1;
            u0[0] = f2b(v0.x); u0[1] = f2b(v0.y); u0[2] = f2b(v0.z); u0[3] = f2b(v0.w);
            u0[4] = f2b(v1.x); u0[5] = f2b(v1.y); u0[6] = f2b(v1.z); u0[7] = f2b(v1.w);
            u1[0] = f2b(v2.x); u1[1] = f2b(v2.y); u1[2] = f2b(v2.z); u1[3] = f2b(v2.w);
            u1[4] = f2b(v3.x); u1[5] = f2b(v3.y); u1[6] = f2b(v3.z); u1[7] = f2b(v3.w);
            *(ushort8*)&As[a_row][a_kq]     = u0;
            *(ushort8*)&As[a_row][a_kq + 8] = u1;
        }
        {
            const ushort_t* wp = WT + (size_t)(col0 + a_row) * K + (k0 + a_kq);
            *(ushort8*)&Bs[a_row][a_kq]     = *(const ushort8*)(wp);
            *(ushort8*)&Bs[a_row][a_kq + 8] = *(const ushort8*)(wp + 8);
        }
        __syncthreads();

        short8v a[4], b[4];
#pragma unroll
        for (int mb = 0; mb < 4; ++mb)
            a[mb] = *(const short8v*)&As[wm + mb * 16 + m16][kof];
#pragma unroll
        for (int nb = 0; nb < 4; ++nb)
            b[nb] = *(const short8v*)&Bs[wn + nb * 16 + m16][kof];
#pragma unroll
        for (int mb = 0; mb < 4; ++mb)
#pragma unroll
            for (int nb = 0; nb < 4; ++nb)
                acc[mb][nb] = __builtin_amdgcn_mfma_f32_16x16x32_bf16(
                    a[mb], b[nb], acc[mb][nb], 0, 0, 0);
        __syncthreads();
    }

    const int r_base = row0 + wm + (lane >> 4) * 4;
#pragma unroll
    for (int nb = 0; nb < 4; ++nb) {
        const int col = col0 + wn + nb * 16 + m16;
        const float bv = bias[col];
#pragma unroll
        for (int mb = 0; mb < 4; ++mb) {
#pragma unroll
            for (int r = 0; r < 4; ++r) {
                const int row = r_base + mb * 16 + r;
                const float v = acc[mb][nb][r] + bv;
                if (col < 192) {
                    qb[(size_t)row * 192 + col] = f2b(v);
                } else if (col < 576) {
                    const int u = col - 192, h = u >> 5, c = u & 31;
                    if (c < 16) kbt[(size_t)row * 192 + h * 16 + c] = f2b(v);
                    else        vbt[(size_t)row * 192 + h * 16 + (c - 16)] = f2b(v);
                } else {
                    praw[(size_t)row * 576 + (col - 576)] = f2h(v);
                }
            }
        }
    }
}

// ---------------------------------------------------------------------------
// z-projection GEMM, single-stage (K=128 staged once, 1 barrier).
// ---------------------------------------------------------------------------
__global__ __launch_bounds__(256) void gemm_zproj(
    const float* __restrict__ Z, const ushort_t* __restrict__ WcT,
    const float* __restrict__ bc, ushort_t* __restrict__ zph)
{
    __shared__ ushort_t zt[64][136];
    __shared__ ushort_t wt[64][136];

    const int tid  = threadIdx.x;
    const int row0 = blockIdx.x * 64;
    const int wave = tid >> 6;
    const int lane = tid & 63;
    const int wm = (wave >> 1) * 32;
    const int wn = (wave & 1) * 32;
    const int m16 = lane & 15;
    const int kof = (lane >> 4) * 8;

    const int r  = tid >> 2;
    const int qt = (tid & 3) * 32;

    {
        const float* ap = Z + (size_t)(row0 + r) * 128 + qt;
#pragma unroll
        for (int i = 0; i < 4; ++i) {
            float4 v0 = *(const float4*)(ap + i * 8);
            float4 v1 = *(const float4*)(ap + i * 8 + 4);
            ushort8 u;
            u[0] = f2b(v0.x); u[1] = f2b(v0.y); u[2] = f2b(v0.z); u[3] = f2b(v0.w);
            u[4] = f2b(v1.x); u[5] = f2b(v1.y); u[6] = f2b(v1.z); u[7] = f2b(v1.w);
            *(ushort8*)&zt[r][qt + i * 8] = u;
        }
    }
    {
        const ushort_t* wp = WcT + (size_t)r * 128 + qt;
        *(ushort8*)&wt[r][qt]      = *(const ushort8*)(wp);
        *(ushort8*)&wt[r][qt + 8]  = *(const ushort8*)(wp + 8);
        *(ushort8*)&wt[r][qt + 16] = *(const ushort8*)(wp + 16);
        *(ushort8*)&wt[r][qt + 24] = *(const ushort8*)(wp + 24);
    }
    __syncthreads();

    f32x4 acc[2][2];
#pragma unroll
    for (int i = 0; i < 2; ++i)
#pragma unroll
        for (int j = 0; j < 2; ++j) acc[i][j] = (f32x4)0.0f;

#pragma unroll
    for (int ks = 0; ks < 4; ++ks) {
        short8v a[2], b[2];
        a[0] = *(const short8v*)&zt[wm + m16][ks * 32 + kof];
        a[1] = *(const short8v*)&zt[wm + 16 + m16][ks * 32 + kof];
        b[0] = *(const short8v*)&wt[wn + m16][ks * 32 + kof];
        b[1] = *(const short8v*)&wt[wn + 16 + m16][ks * 32 + kof];
#pragma unroll
        for (int mb = 0; mb < 2; ++mb)
#pragma unroll
            for (int nb = 0; nb < 2; ++nb)
                acc[mb][nb] = __builtin_amdgcn_mfma_f32_16x16x32_bf16(
                    a[mb], b[nb], acc[mb][nb], 0, 0, 0);
    }

    const int r_base = row0 + wm + (lane >> 4) * 4;
#pragma unroll
    for (int nb = 0; nb < 2; ++nb) {
        const int col = wn + nb * 16 + m16;
        if (col >= 44) continue;
        const float bv = bc[col];
#pragma unroll
        for (int mb = 0; mb < 2; ++mb) {
#pragma unroll
            for (int rr = 0; rr < 4; ++rr) {
                zph[(size_t)(r_base + mb * 16 + rr) * 48 + col] = f2b(acc[mb][nb][rr] + bv);
            }
        }
    }
}

// ---------------------------------------------------------------------------
// out-GEMM: A bf16 (catb), B = WoutT[384][960] bf16, 64x64, XCD swizzle.
// ---------------------------------------------------------------------------
__global__ __launch_bounds__(256) void gemm_out(
    const ushort_t* __restrict__ A, const ushort_t* __restrict__ WT,
    const float* __restrict__ bias, float* __restrict__ C)
{
    __shared__ ushort_t As[64][40];
    __shared__ ushort_t Bs[64][40];

    const int tid  = threadIdx.x;
    const int ncol = 6;
    const int id   = blockIdx.x;
    const int xcd  = id & 7;
    const int qq   = id >> 3;
    const int row0 = ((qq / ncol) * 8 + xcd) * 64;
    const int col0 = (qq % ncol) * 64;
    const int K = 960, P = 384;

    const int wave = tid >> 6;
    const int lane = tid & 63;
    const int wm = (wave >> 1) * 32;
    const int wn = (wave & 1) * 32;
    const int m16 = lane & 15;
    const int kof = (lane >> 4) * 8;

    const int a_row = tid >> 2;
    const int a_kq  = (tid & 3) * 8;

    f32x4 acc[2][2];
#pragma unroll
    for (int i = 0; i < 2; ++i)
#pragma unroll
        for (int j = 0; j < 2; ++j) acc[i][j] = (f32x4)0.0f;

    for (int k0 = 0; k0 < K; k0 += 32) {
        *(ushort8*)&As[a_row][a_kq] =
            *(const ushort8*)(A + (size_t)(row0 + a_row) * K + (k0 + a_kq));
        *(ushort8*)&Bs[a_row][a_kq] =
            *(const ushort8*)(WT + (size_t)(col0 + a_row) * K + (k0 + a_kq));
        __syncthreads();

        short8v a[2], b[2];
#pragma unroll
        for (int mb = 0; mb < 2; ++mb)
            a[mb] = *(const short8v*)&As[wm + mb * 16 + m16][kof];
#pragma unroll
        for (int nb = 0; nb < 2; ++nb)
            b[nb] = *(const short8v*)&Bs[wn + nb * 16 + m16][kof];
#pragma unroll
        for (int mb = 0; mb < 2; ++mb)
#pragma unroll
            for (int nb = 0; nb < 2; ++nb)
                acc[mb][nb] = __builtin_amdgcn_mfma_f32_16x16x32_bf16(
                    a[mb], b[nb], acc[mb][nb], 0, 0, 0);
        __syncthreads();
    }

    const int r_base = row0 + wm + (lane >> 4) * 4;
#pragma unroll
    for (int nb = 0; nb < 2; ++nb) {
        const int col = col0 + wn + nb * 16 + m16;
        const float bv = bias[col];
#pragma unroll
        for (int mb = 0; mb < 2; ++mb) {
#pragma unroll
            for (int r = 0; r < 4; ++r) {
                C[(size_t)(r_base + mb * 16 + r) * P + col] = acc[mb][nb][r] + bv;
            }
        }
    }
}

// ---------------------------------------------------------------------------
// prep_pts: praw fp16 in; q_pts fp32, kpt fp16, vpt bf16 out. 192 tasks/node.
// ---------------------------------------------------------------------------
__global__ void prep_pts(const ushort_t* __restrict__ praw,
                         const float* __restrict__ rot,
                         const float* __restrict__ trans,
                         float* __restrict__ q_pts,
                         ushort_t* __restrict__ kpt,
                         ushort_t* __restrict__ vpt)
{
    int t = blockIdx.x * 256 + threadIdx.x;
    if (t >= N_NODES * 192) return;
    const int n = t / 192;
    const int m = t % 192;
    const ushort_t* row = praw + (size_t)n * 576;
    const float* R  = rot + n * 9;
    const float* tr = trans + n * 3;
    float X, Y, Z;
    if (m < 48) { X = h2f(row[m]);       Y = h2f(row[48 + m]);   Z = h2f(row[96 + m]); }
    else { const int pt = m - 48;
           X = h2f(row[144 + pt]);  Y = h2f(row[288 + pt]); Z = h2f(row[432 + pt]); }
    const float gx = R[0] * X + R[1] * Y + R[2] * Z + tr[0];
    const float gy = R[3] * X + R[4] * Y + R[5] * Z + tr[1];
    const float gz = R[6] * X + R[7] * Y + R[8] * Z + tr[2];
    if (m < 48) {
        const int h = m >> 2, p = m & 3;
        float* dst = q_pts + (size_t)n * 144 + h * 12 + p * 3;
        dst[0] = gx; dst[1] = gy; dst[2] = gz;
    } else {
        const int pt = m - 48, h = pt / 12, p = pt % 12;
        if (p < 4) {
            ushort_t* dst = kpt + (size_t)n * 144 + h * 12 + p * 3;
            dst[0] = f2h(gx); dst[1] = f2h(gy); dst[2] = f2h(gz);
        } else {
            ushort_t* dst = vpt + (size_t)n * 288 + h * 24 + (p - 4) * 3;
            dst[0] = f2b(gx); dst[1] = f2b(gy); dst[2] = f2b(gz);
        }
    }
}

// ---------------------------------------------------------------------------
// attention (round-13 measured-best config): one node / 256 thr per block,
// de-staged direct gather, separate tables, kpt fp16.
// ---------------------------------------------------------------------------
__global__ __launch_bounds__(256, 8) void attn_kernel(
    const ushort_t* __restrict__ qb,       // N x 192 bf16
    const ushort_t* __restrict__ kbt,      // N x 192 bf16
    const ushort_t* __restrict__ vbt,      // N x 192 bf16
    const float* __restrict__ q_pts,       // N x 144 f32
    const ushort_t* __restrict__ kpt,      // N x 144 fp16
    const ushort_t* __restrict__ vpt,      // N x 288 bf16
    const ushort_t* __restrict__ zph,      // (N*K) x 48 bf16 (44 valid)
    const int*   __restrict__ eidx,
    const float* __restrict__ mask,
    const float* __restrict__ rot,
    const float* __restrict__ trans,
    const float* __restrict__ head_weights,
    ushort_t* __restrict__ catb)           // N x 960 bf16
{
    const int n   = blockIdx.x;
    const int tid = threadIdx.x;

    __shared__ ushort_t zp[32][48];
    __shared__ float q_s[192];
    __shared__ float qp_s[144];
    __shared__ float a_s[12][33];
    __shared__ float opt[288];
    __shared__ int   idx_s[32];
    __shared__ float madd_s[32];
    __shared__ float R_s[9];
    __shared__ float t_s[3];
    __shared__ float hw_s[12];

    // ---- phase 0: stage reused data ----
    for (int i = tid; i < 192; i += 256) q_s[i]  = b2f(qb[(size_t)n * 192 + i]);
    for (int i = tid; i < 144; i += 256) qp_s[i] = q_pts[(size_t)n * 144 + i];
    if (tid < 32) {
        const int ix = eidx[n * 32 + tid];
        idx_s[tid]  = ix;
        madd_s[tid] = 100000.0f * (mask[ix] - 1.0f);
    }
    if (tid >= 32 && tid < 41) R_s[tid - 32]  = rot[n * 9 + (tid - 32)];
    if (tid >= 41 && tid < 44) t_s[tid - 41]  = trans[n * 3 + (tid - 41)];
    if (tid >= 44 && tid < 56) {
        float x = head_weights[tid - 44];
        hw_s[tid - 44] = log1pf(__expf(x)) * 0.13608276348795434f; // softplus*sqrt(1/54)
    }
    if (tid < 192) {
        const int r = tid / 6, sg = tid % 6;
        *(ushort8*)&zp[r][sg * 8] =
            *(const ushort8*)(zph + ((size_t)n * 32 + r) * 48 + sg * 8);
    }
    __syncthreads();

    // ---- phase 1: logits, direct gather (kpt fp16) ----
    for (int t = tid; t < 384; t += 256) {
        const int h = t >> 5, j = t & 31;
        const int ix = idx_s[j];
        const ushort_t* kr = kbt + (size_t)ix * 192 + h * 16;
        ushort8 k0 = *(const ushort8*)(kr);
        ushort8 k1 = *(const ushort8*)(kr + 8);
        const ushort_t* kpr = kpt + (size_t)ix * 144 + h * 12;
        ushort4v p0 = *(const ushort4v*)(kpr);
        ushort4v p1 = *(const ushort4v*)(kpr + 4);
        ushort4v p2 = *(const ushort4v*)(kpr + 8);

        const float* qh = q_s + h * 16;
        float dot = 0.0f;
#pragma unroll
        for (int c = 0; c < 8; ++c) dot += qh[c] * b2f(k0[c]);
#pragma unroll
        for (int c = 0; c < 8; ++c) dot += qh[8 + c] * b2f(k1[c]);

        const float* qp = qp_s + h * 12;
        float d, pt = 0.0f;
        d = qp[0]  - h2f(p0[0]); pt += d * d;  d = qp[1]  - h2f(p0[1]); pt += d * d;
        d = qp[2]  - h2f(p0[2]); pt += d * d;  d = qp[3]  - h2f(p0[3]); pt += d * d;
        d = qp[4]  - h2f(p1[0]); pt += d * d;  d = qp[5]  - h2f(p1[1]); pt += d * d;
        d = qp[6]  - h2f(p1[2]); pt += d * d;  d = qp[7]  - h2f(p1[3]); pt += d * d;
        d = qp[8]  - h2f(p2[0]); pt += d * d;  d = qp[9]  - h2f(p2[1]); pt += d * d;
        d = qp[10] - h2f(p2[2]); pt += d * d;  d = qp[11] - h2f(p2[3]); pt += d * d;

        a_s[h][j] = 0.14433756729740643f * dot
                  + 0.5773502691896258f * b2f(zp[j][h])
                  - 0.5f * hw_s[h] * pt
                  + madd_s[j];
    }
    __syncthreads();

    // ---- phase 2: parallel softmax (96 threads, 8-lane shuffle groups) ----
    if (tid < 96) {
        const int h = tid >> 3, g = tid & 7;
        float a0 = a_s[h][g * 4 + 0], a1 = a_s[h][g * 4 + 1];
        float a2 = a_s[h][g * 4 + 2], a3 = a_s[h][g * 4 + 3];
        float m = fmaxf(fmaxf(a0, a1), fmaxf(a2, a3));
        m = fmaxf(m, __shfl_xor(m, 1)); m = fmaxf(m, __shfl_xor(m, 2));
        m = fmaxf(m, __shfl_xor(m, 4));
        float e0 = __expf(a0 - m), e1 = __expf(a1 - m);
        float e2 = __expf(a2 - m), e3 = __expf(a3 - m);
        float s = e0 + e1 + e2 + e3;
        s += __shfl_xor(s, 1); s += __shfl_xor(s, 2); s += __shfl_xor(s, 4);
        const float inv = 1.0f / s;
        a_s[h][g * 4 + 0] = e0 * inv; a_s[h][g * 4 + 1] = e1 * inv;
        a_s[h][g * 4 + 2] = e2 * inv; a_s[h][g * 4 + 3] = e3 * inv;
    }
    __syncthreads();

    // ---- phase 3: weighted sums, wave-coalesced direct reads ----
    ushort_t* catn = catb + (size_t)n * 960;
    if (tid < 48) {                      // o: (h, c-quad)
        const int h = tid >> 2, cq = tid & 3;
        const ushort_t* base = vbt + h * 16 + cq * 4;
        float s0 = 0, s1 = 0, s2 = 0, s3 = 0;
#pragma unroll 8
        for (int j = 0; j < 32; ++j) {
            const int ix = idx_s[j];
            const float aj = a_s[h][j];
            ushort4v v = *(const ushort4v*)(base + (size_t)ix * 192);
            s0 += aj * b2f(v[0]); s1 += aj * b2f(v[1]);
            s2 += aj * b2f(v[2]); s3 += aj * b2f(v[3]);
        }
        ushort4v o = { f2b(s0), f2b(s1), f2b(s2), f2b(s3) };
        *(ushort4v*)&catn[h * 16 + cq * 4] = o;
    } else if (tid < 120) {              // o_pt: (h, quad of 24)
        const int u = tid - 48;
        const int h = u / 6, rq = u % 6;
        const ushort_t* base = vpt + h * 24 + rq * 4;
        float s0 = 0, s1 = 0, s2 = 0, s3 = 0;
#pragma unroll 8
        for (int j = 0; j < 32; ++j) {
            const int ix = idx_s[j];
            const float aj = a_s[h][j];
            ushort4v v = *(const ushort4v*)(base + (size_t)ix * 288);
            s0 += aj * b2f(v[0]); s1 += aj * b2f(v[1]);
            s2 += aj * b2f(v[2]); s3 += aj * b2f(v[3]);
        }
        float* od = opt + h * 24 + rq * 4;
        od[0] = s0; od[1] = s1; od[2] = s2; od[3] = s3;
    } else if (tid < 216) {              // o_pair: (h, c-quad of 32)
        const int u = tid - 120;
        const int h = u >> 3, cq = u & 7;
        float s0 = 0, s1 = 0, s2 = 0, s3 = 0;
#pragma unroll 8
        for (int j = 0; j < 32; ++j) {
            const float aj = a_s[h][j];
            ushort4v zv = *(const ushort4v*)&zp[j][12 + cq * 4];
            s0 += aj * b2f(zv[0]); s1 += aj * b2f(zv[1]);
            s2 += aj * b2f(zv[2]); s3 += aj * b2f(zv[3]);
        }
        ushort4v o = { f2b(s0), f2b(s1), f2b(s2), f2b(s3) };
        *(ushort4v*)&catn[576 + h * 32 + cq * 4] = o;
    }
    __syncthreads();

    // ---- phase 4: rotate back + norms ----
    if (tid < 96) {
        const int h = tid >> 3, p = tid & 7;
        const float* ob = opt + h * 24 + p * 3;
        float gx = ob[0] - t_s[0];
        float gy = ob[1] - t_s[1];
        float gz = ob[2] - t_s[2];
        float lx = R_s[0] * gx + R_s[3] * gy + R_s[6] * gz;
        float ly = R_s[1] * gx + R_s[4] * gy + R_s[7] * gz;
        float lz = R_s[2] * gx + R_s[5] * gy + R_s[8] * gz;
        const int hp = h * 8 + p;
        catn[192 + hp] = f2b(lx);
        catn[288 + hp] = f2b(ly);
        catn[384 + hp] = f2b(lz);
        catn[480 + hp] = f2b(sqrtf(lx * lx + ly * ly + lz * lz + 1e-8f));
    }
}

// ---------------------------------------------------------------------------
extern "C" void kernel_launch(void* const* d_in, const int* in_sizes, int n_in,
                              void* d_out, int out_size, void* d_ws, size_t ws_size,
                              hipStream_t stream)
{
    const float* s     = (const float*)d_in[0];
    const float* z     = (const float*)d_in[1];
    const int*   eidx  = (const int*)  d_in[2];
    const float* rot   = (const float*)d_in[3];
    const float* trans = (const float*)d_in[4];
    const float* mask  = (const float*)d_in[5];
    const float* w_q   = (const float*)d_in[6];
    const float* b_q   = (const float*)d_in[7];
    const float* w_kv  = (const float*)d_in[8];
    const float* b_kv  = (const float*)d_in[9];
    const float* w_qp  = (const float*)d_in[10];
    const float* b_qp  = (const float*)d_in[11];
    const float* w_kvp = (const float*)d_in[12];
    const float* b_kvp = (const float*)d_in[13];
    const float* w_b   = (const float*)d_in[14];
    const float* b_b   = (const float*)d_in[15];
    const float* w_dz  = (const float*)d_in[16];
    const float* b_dz  = (const float*)d_in[17];
    const float* hw    = (const float*)d_in[18];
    const float* w_out = (const float*)d_in[19];
    const float* b_out = (const float*)d_in[20];
    float* out = (float*)d_out;

    float* ws = (float*)d_ws;
    size_t off = 0;
    ushort_t* qb    = (ushort_t*)(ws + off); off += (size_t)N_NODES * 96;   // 192 bf16
    ushort_t* kbt   = (ushort_t*)(ws + off); off += (size_t)N_NODES * 96;
    ushort_t* vbt   = (ushort_t*)(ws + off); off += (size_t)N_NODES * 96;
    ushort_t* praw  = (ushort_t*)(ws + off); off += (size_t)N_NODES * 288;  // 576 fp16
    float* q_pts    = ws + off;              off += (size_t)N_NODES * 144;
    ushort_t* kpt   = (ushort_t*)(ws + off); off += (size_t)N_NODES * 72;   // 144 fp16
    ushort_t* vpt   = (ushort_t*)(ws + off); off += (size_t)N_NODES * 144;  // 288 bf16
    ushort_t* zph   = (ushort_t*)(ws + off); off += (size_t)N_NODES * KNN * 24; // 48 bf16
    ushort_t* catb  = (ushort_t*)(ws + off); off += (size_t)N_NODES * 480;      // 960 bf16
    ushort_t* WallT = (ushort_t*)(ws + off); off += N_WALLT / 2;
    float* ball     = ws + off;              off += 1152;
    ushort_t* WcatT = (ushort_t*)(ws + off); off += N_WCATT / 2;
    float* bcat     = ws + off;              off += 44;
    ushort_t* WoutT = (ushort_t*)(ws + off); off += N_WOUTT / 2;

    // 1) all weight tables (one launch)
    build_weights<<<(BW_TOTAL + 255) / 256, 256, 0, stream>>>(
        w_q, b_q, w_kv, b_kv, w_qp, b_qp, w_kvp, b_kvp,
        w_b, b_b, w_dz, b_dz, w_out, WallT, ball, WcatT, bcat, WoutT);

    // 2) s-projection with split epilogue (qb | kbt/vbt | praw fp16)
    gemm_sproj<<<(N_NODES / 128) * 9, 256, 0, stream>>>(
        s, WallT, ball, qb, kbt, vbt, praw);

    // 3) z-projection -> bf16 zph (single-stage streaming)
    gemm_zproj<<<(N_NODES * KNN) / 64, 256, 0, stream>>>(z, WcatT, bcat, zph);

    // 4) point transforms
    prep_pts<<<(N_NODES * 192 + 255) / 256, 256, 0, stream>>>(
        praw, rot, trans, q_pts, kpt, vpt);

    // 5) attention (single-node blocks — measured best)
    attn_kernel<<<N_NODES, 256, 0, stream>>>(
        qb, kbt, vbt, q_pts, kpt, vpt, zph, eidx, mask, rot, trans, hw, catb);

    // 6) output projection
    gemm_out<<<(N_NODES / 64) * 6, 256, 0, stream>>>(catb, WoutT, b_out, out);
}